// Round 1
// baseline (1101.157 us; speedup 1.0000x reference)
//
#include <hip/hip_runtime.h>
#include <math.h>

// ---------------- constants ----------------
#define NIMG   4
#define NPROP  2048
#define MTOT   8192          // NIMG*NPROP
#define FIN    12544
#define HID    1024
#define NC     91            // classes incl background
#define NCB    512           // padded combined cls(91)+bbox(364)=455 -> 512
#define DETS   100
#define CAPMAX (NPROP * (NC - 1))   // 184320 per image

typedef __attribute__((ext_vector_type(8))) short short8;
typedef __attribute__((ext_vector_type(4))) float f32x4;

__device__ __forceinline__ unsigned short f2bf(float f) {
  union { float f; unsigned u; } v; v.f = f;
  unsigned r = v.u + 0x7fffu + ((v.u >> 16) & 1u);  // RNE
  return (unsigned short)(r >> 16);
}

// ---------------- transpose + fp32->bf16 convert ----------------
// in: [K][N] fp32 row-major; out: [row_off + n][k] bf16, leading dim out_ld
__global__ void transpose_cvt(const float* __restrict__ in, unsigned short* __restrict__ out,
                              int K, int N, int row_off, int out_ld) {
  __shared__ float tile[32][33];
  int k0 = blockIdx.y * 32, n0 = blockIdx.x * 32;
  int tx = threadIdx.x, ty = threadIdx.y;
#pragma unroll
  for (int i = 0; i < 4; ++i) {
    int r = ty + i * 8;
    if (k0 + r < K && n0 + tx < N)
      tile[r][tx] = in[(size_t)(k0 + r) * N + (n0 + tx)];
  }
  __syncthreads();
#pragma unroll
  for (int i = 0; i < 4; ++i) {
    int r = ty + i * 8;
    if (n0 + r < N && k0 + tx < K)
      out[(size_t)(row_off + n0 + r) * out_ld + (k0 + tx)] = f2bf(tile[tx][r]);
  }
}

// zero pad rows of Wcbt, build combined bias, zero candidate counters
__global__ void prep_misc(unsigned short* __restrict__ Wcbt, float* __restrict__ bias_cb,
                          const float* __restrict__ cls_b, const float* __restrict__ bbox_b,
                          int* __restrict__ ccount) {
  int i = blockIdx.x * blockDim.x + threadIdx.x;
  int stride = gridDim.x * blockDim.x;
  for (int j = i; j < 57 * 1024; j += stride) Wcbt[455 * 1024 + j] = 0;          // pad rows 455..511
  for (int j = i; j < NCB; j += stride)
    bias_cb[j] = (j < 91) ? cls_b[j] : ((j < 455) ? bbox_b[j - 91] : 0.0f);
  if (i < NIMG) ccount[i] = 0;
}

// ---------------- NT GEMM: C[m][n] = act(sum_k A[m][k]*Bt[n][k] + bias[n]) ----------------
// 128x128 tile, BK=64, 4 waves (2x2), each wave 64x64 via 4x4 mfma_16x16x32_bf16
template <bool AFP32, bool RELU, bool OUTBF16>
__global__ __launch_bounds__(256) void gemm_nt(const void* __restrict__ Av,
                                               const unsigned short* __restrict__ Bt,
                                               const float* __restrict__ bias,
                                               void* __restrict__ Cv,
                                               int M, int N, int K) {
  __shared__ __align__(16) short As[128 * 72];   // row stride 72 bf16 = 144B (2-way only)
  __shared__ __align__(16) short Bs[128 * 72];
  const int tid  = threadIdx.x;
  const int lane = tid & 63;
  const int wid  = tid >> 6;
  const int wm   = (wid >> 1) * 64;
  const int wn   = (wid & 1) * 64;
  const int m0   = blockIdx.y * 128, n0 = blockIdx.x * 128;
  const int lcol = lane & 15;
  const int lk8  = (lane >> 4) * 8;

  f32x4 acc[4][4];
#pragma unroll
  for (int a = 0; a < 4; ++a)
#pragma unroll
    for (int b = 0; b < 4; ++b)
#pragma unroll
      for (int r = 0; r < 4; ++r) acc[a][b][r] = 0.0f;

  for (int k0 = 0; k0 < K; k0 += 64) {
    // ---- stage A and B tiles into LDS (256 thr x 4 slots x 8 bf16 = 128x64) ----
#pragma unroll
    for (int i = 0; i < 4; ++i) {
      int s   = tid + i * 256;
      int row = s >> 3;
      int kc  = (s & 7) << 3;
      short8 va;
      if constexpr (AFP32) {
        const float* gp = (const float*)Av + (size_t)(m0 + row) * K + (k0 + kc);
        float4 u = *(const float4*)gp;
        float4 w = *(const float4*)(gp + 4);
        va[0] = (short)f2bf(u.x); va[1] = (short)f2bf(u.y);
        va[2] = (short)f2bf(u.z); va[3] = (short)f2bf(u.w);
        va[4] = (short)f2bf(w.x); va[5] = (short)f2bf(w.y);
        va[6] = (short)f2bf(w.z); va[7] = (short)f2bf(w.w);
      } else {
        va = *(const short8*)((const unsigned short*)Av + (size_t)(m0 + row) * K + (k0 + kc));
      }
      *(short8*)&As[row * 72 + kc] = va;
      short8 vb = *(const short8*)(Bt + (size_t)(n0 + row) * K + (k0 + kc));
      *(short8*)&Bs[row * 72 + kc] = vb;
    }
    __syncthreads();
    // ---- compute: 2 K-steps of 32 ----
#pragma unroll
    for (int kk = 0; kk < 64; kk += 32) {
      short8 af[4], bf[4];
#pragma unroll
      for (int im = 0; im < 4; ++im)
        af[im] = *(const short8*)&As[(wm + im * 16 + lcol) * 72 + kk + lk8];
#pragma unroll
      for (int in = 0; in < 4; ++in)
        bf[in] = *(const short8*)&Bs[(wn + in * 16 + lcol) * 72 + kk + lk8];
#pragma unroll
      for (int im = 0; im < 4; ++im)
#pragma unroll
        for (int in = 0; in < 4; ++in)
          acc[im][in] = __builtin_amdgcn_mfma_f32_16x16x32_bf16(af[im], bf[in], acc[im][in], 0, 0, 0);
    }
    __syncthreads();
  }

  // ---- epilogue: C/D layout col=lane&15, row=(lane>>4)*4+r ----
  const int r0 = (lane >> 4) * 4;
#pragma unroll
  for (int im = 0; im < 4; ++im) {
#pragma unroll
    for (int in = 0; in < 4; ++in) {
      int gn = n0 + wn + in * 16 + lcol;
      float bv = bias[gn];
#pragma unroll
      for (int r = 0; r < 4; ++r) {
        int gm = m0 + wm + im * 16 + r0 + r;
        float vv = acc[im][in][r] + bv;
        if (RELU) vv = fmaxf(vv, 0.0f);
        if (OUTBF16) ((unsigned short*)Cv)[(size_t)gm * N + gn] = f2bf(vv);
        else         ((float*)Cv)[(size_t)gm * N + gn] = vv;
      }
    }
  }
}

// ---------------- candidate generation (softmax + decode + threshold + compact) ----------------
__global__ void candgen(const float* __restrict__ out3, const float* __restrict__ props,
                        float* __restrict__ cscore, float* __restrict__ cbox,
                        int* __restrict__ clabel, int* __restrict__ ccount, int CAP) {
  int g = blockIdx.x * blockDim.x + threadIdx.x;
  if (g >= MTOT) return;
  int img = g >> 11;
  const float* row = out3 + (size_t)g * NCB;
  float mx = row[0];
  for (int c = 1; c < NC; ++c) mx = fmaxf(mx, row[c]);
  float den = 0.0f;
  for (int c = 0; c < NC; ++c) den += expf(row[c] - mx);
  float inv = 1.0f / den;

  float px1 = props[(size_t)g * 4 + 0], py1 = props[(size_t)g * 4 + 1];
  float px2 = props[(size_t)g * 4 + 2], py2 = props[(size_t)g * 4 + 3];
  float w = px2 - px1, h = py2 - py1;
  float cx = px1 + 0.5f * w, cy = py1 + 0.5f * h;

  for (int c = 1; c < NC; ++c) {
    float s = expf(row[c] - mx) * inv;
    if (s > 0.05f) {
      float dx = row[91 + c * 4 + 0] / 10.0f;
      float dy = row[91 + c * 4 + 1] / 10.0f;
      float dw = fminf(row[91 + c * 4 + 2] / 5.0f, 4.135166556742356f);
      float dh = fminf(row[91 + c * 4 + 3] / 5.0f, 4.135166556742356f);
      float pcx = dx * w + cx, pcy = dy * h + cy;
      float pw = expf(dw) * w, ph = expf(dh) * h;
      float x1 = fminf(fmaxf(pcx - 0.5f * pw, 0.0f), 800.0f);
      float x2 = fminf(fmaxf(pcx + 0.5f * pw, 0.0f), 800.0f);
      float y1 = fminf(fmaxf(pcy - 0.5f * ph, 0.0f), 800.0f);
      float y2 = fminf(fmaxf(pcy + 0.5f * ph, 0.0f), 800.0f);
      if (x2 - x1 >= 0.01f && y2 - y1 >= 0.01f) {
        int idx = atomicAdd(&ccount[img], 1);
        if (idx < CAP) {
          size_t o = (size_t)img * CAP + idx;
          cscore[o] = s;
          clabel[o] = c;
          cbox[o * 4 + 0] = x1; cbox[o * 4 + 1] = y1;
          cbox[o * 4 + 2] = x2; cbox[o * 4 + 3] = y2;
        }
      }
    }
  }
}

// ---------------- sequential NMS over compacted candidates; one block per image ----------------
__global__ void nms_kernel(float* __restrict__ cscore, const float* __restrict__ cbox,
                           const int* __restrict__ clabel, const int* __restrict__ ccount,
                           float* __restrict__ out, int CAP) {
  int img = blockIdx.x;
  int tid = threadIdx.x;
  int V = ccount[img]; if (V > CAP) V = CAP;
  float* sc = cscore + (size_t)img * CAP;
  const float* bx = cbox + (size_t)img * CAP * 4;
  const int* lb = clabel + (size_t)img * CAP;
  float* ob = out + (size_t)img * DETS * 4;                       // boxes  [4,100,4]
  float* os = out + (size_t)NIMG * DETS * 4 + (size_t)img * DETS; // scores [4,100]
  float* ol = out + (size_t)NIMG * DETS * 5 + (size_t)img * DETS; // labels [4,100]

  for (int t = tid; t < DETS; t += blockDim.x) {
    ob[t * 4 + 0] = 0.0f; ob[t * 4 + 1] = 0.0f; ob[t * 4 + 2] = 0.0f; ob[t * 4 + 3] = 0.0f;
    os[t] = 0.0f; ol[t] = 0.0f;
  }

  __shared__ float rs[256];
  __shared__ int   ri[256];
  __shared__ float bb[5];   // offset box x1,y1,x2,y2 + area

  for (int d = 0; d < DETS; ++d) {
    __syncthreads();  // protects rs/ri WAR across iterations + initial zeroing
    float bs = -INFINITY; int bi = -1;
    for (int t = tid; t < V; t += blockDim.x)
      if (sc[t] > bs) { bs = sc[t]; bi = t; }
    rs[tid] = bs; ri[tid] = bi;
    __syncthreads();
    for (int off = 128; off > 0; off >>= 1) {
      if (tid < off && rs[tid + off] > rs[tid]) { rs[tid] = rs[tid + off]; ri[tid] = ri[tid + off]; }
      __syncthreads();
    }
    int best = ri[0]; float bscore = rs[0];   // uniform across block
    if (best >= 0 && bscore > -INFINITY) {
      if (tid == 0) {
        ob[d * 4 + 0] = bx[best * 4 + 0]; ob[d * 4 + 1] = bx[best * 4 + 1];
        ob[d * 4 + 2] = bx[best * 4 + 2]; ob[d * 4 + 3] = bx[best * 4 + 3];
        os[d] = bscore;
        ol[d] = (float)lb[best];
        float offv = (float)lb[best] * 801.0f;
        float ox1 = bx[best * 4 + 0] + offv, oy1 = bx[best * 4 + 1] + offv;
        float ox2 = bx[best * 4 + 2] + offv, oy2 = bx[best * 4 + 3] + offv;
        bb[0] = ox1; bb[1] = oy1; bb[2] = ox2; bb[3] = oy2;
        bb[4] = (ox2 - ox1) * (oy2 - oy1);
      }
      __syncthreads();
      float bx1 = bb[0], by1 = bb[1], bx2 = bb[2], by2 = bb[3], barea = bb[4];
      for (int t = tid; t < V; t += blockDim.x) {
        float offv = (float)lb[t] * 801.0f;
        float tx1 = bx[t * 4 + 0] + offv, ty1 = bx[t * 4 + 1] + offv;
        float tx2 = bx[t * 4 + 2] + offv, ty2 = bx[t * 4 + 3] + offv;
        float ltx = fmaxf(tx1, bx1), lty = fmaxf(ty1, by1);
        float rbx = fminf(tx2, bx2), rby = fminf(ty2, by2);
        float inter = fmaxf(rbx - ltx, 0.0f) * fmaxf(rby - lty, 0.0f);
        float areat = (tx2 - tx1) * (ty2 - ty1);
        float uni = fmaxf(areat + barea - inter, 1e-6f);
        if (inter / uni > 0.5f) sc[t] = -INFINITY;
      }
    }
  }
}

// ---------------- host ----------------
extern "C" void kernel_launch(void* const* d_in, const int* in_sizes, int n_in,
                              void* d_out, int out_size, void* d_ws, size_t ws_size,
                              hipStream_t stream) {
  const float* box_features = (const float*)d_in[0];
  const float* proposals    = (const float*)d_in[1];
  const float* fc6_w = (const float*)d_in[2];
  const float* fc6_b = (const float*)d_in[3];
  const float* fc7_w = (const float*)d_in[4];
  const float* fc7_b = (const float*)d_in[5];
  const float* cls_w = (const float*)d_in[6];
  const float* cls_b = (const float*)d_in[7];
  const float* bbox_w = (const float*)d_in[8];
  const float* bbox_b = (const float*)d_in[9];

  char* ws = (char*)d_ws;
  size_t off = 0;
  unsigned short* W6t  = (unsigned short*)(ws + off); off += (size_t)HID * FIN * 2;   // 25.7 MB
  unsigned short* W7t  = (unsigned short*)(ws + off); off += (size_t)HID * HID * 2;   // 2 MB
  unsigned short* Wcbt = (unsigned short*)(ws + off); off += (size_t)NCB * HID * 2;   // 1 MB
  float* bias_cb       = (float*)(ws + off);          off += (size_t)NCB * 4;
  int*   ccount        = (int*)(ws + off);            off += 256;
  unsigned short* h1   = (unsigned short*)(ws + off); off += (size_t)MTOT * HID * 2;  // 16 MB
  unsigned short* h2   = (unsigned short*)(ws + off); off += (size_t)MTOT * HID * 2;  // 16 MB
  float* out3          = (float*)(ws + off);          off += (size_t)MTOT * NCB * 4;  // 16 MB

  // candidate arrays sized by remaining workspace (96 B per candidate across 4 images)
  int CAP = CAPMAX;
  if (ws_size > off) {
    size_t avail = ws_size - off;
    size_t cap_ws = avail / 96;
    if (cap_ws < (size_t)CAP) CAP = (int)cap_ws;
  } else {
    CAP = 0;
  }
  float* cscore = (float*)(ws + off);
  int*   clabel = (int*)(ws + off + (size_t)NIMG * CAP * 4);
  float* cbox   = (float*)(ws + off + (size_t)NIMG * CAP * 8);

  // ---- weight prep ----
  transpose_cvt<<<dim3(HID / 32, FIN / 32), dim3(32, 8), 0, stream>>>(fc6_w, W6t, FIN, HID, 0, FIN);
  transpose_cvt<<<dim3(HID / 32, HID / 32), dim3(32, 8), 0, stream>>>(fc7_w, W7t, HID, HID, 0, HID);
  transpose_cvt<<<dim3(3,  HID / 32), dim3(32, 8), 0, stream>>>(cls_w,  Wcbt, HID, 91,  0,  HID);
  transpose_cvt<<<dim3(12, HID / 32), dim3(32, 8), 0, stream>>>(bbox_w, Wcbt, HID, 364, 91, HID);
  prep_misc<<<64, 256, 0, stream>>>(Wcbt, bias_cb, cls_b, bbox_b, ccount);

  // ---- MLP head + predictor ----
  // grid.x = n-tiles (fastest) so blocks sharing an A-slab co-run -> A HBM-read ~once via L3
  gemm_nt<true,  true,  true ><<<dim3(HID / 128, MTOT / 128), 256, 0, stream>>>(
      box_features, W6t, fc6_b, h1, MTOT, HID, FIN);
  gemm_nt<false, true,  true ><<<dim3(HID / 128, MTOT / 128), 256, 0, stream>>>(
      h1, W7t, fc7_b, h2, MTOT, HID, HID);
  gemm_nt<false, false, false><<<dim3(NCB / 128, MTOT / 128), 256, 0, stream>>>(
      h2, Wcbt, bias_cb, out3, MTOT, NCB, HID);

  // ---- postprocess ----
  candgen<<<MTOT / 256, 256, 0, stream>>>(out3, proposals, cscore, cbox, clabel, ccount, CAP);
  nms_kernel<<<NIMG, 256, 0, stream>>>(cscore, cbox, clabel, ccount, (float*)d_out, CAP);
}